// Round 9
// baseline (21646.033 us; speedup 1.0000x reference)
//
#include <hip/hip_runtime.h>
#include <math.h>

// Problem constants
// H=256, D_IN=22, T=384, 4H=1024, N_R=N_L=384, H1=1024, H2=512, H3=1024, RRI=2

typedef _Float16 half2_t __attribute__((ext_vector_type(2)));

__device__ __forceinline__ float fast_sig(float x) {
    float e = __expf(-x);
    return __builtin_amdgcn_rcpf(1.f + e);
}
__device__ __forceinline__ float fast_tanh(float x) {
    x = fminf(fmaxf(x, -30.f), 30.f);
    float e = __expf(2.f * x);
    return (e - 1.f) * __builtin_amdgcn_rcpf(e + 1.f);
}

// ---------------------------------------------------------------------------
// prep: b0sum = bih0+bhh0, b1sum = bih1+bhh1, W3sum[n][k] = W3[n][k]+W3[n][512+k],
//       woutT[2c+k] = Wout[k][c]
// ---------------------------------------------------------------------------
__global__ __launch_bounds__(256) void prep_kernel(
    const float* __restrict__ bih0, const float* __restrict__ bhh0,
    const float* __restrict__ bih1, const float* __restrict__ bhh1,
    const float* __restrict__ W3,   const float* __restrict__ Wout,
    float* __restrict__ b0sum, float* __restrict__ b1sum,
    float* __restrict__ W3sum, float* __restrict__ woutT)
{
    int idx = blockIdx.x * 256 + threadIdx.x;
    int stride = gridDim.x * 256;
    if (idx < 2048) {
        b0sum[idx] = bih0[idx] + bhh0[idx];
        b1sum[idx] = bih1[idx] + bhh1[idx];
        woutT[idx] = Wout[(idx & 1) * 1024 + (idx >> 1)];
    }
    for (int i = idx; i < 1024 * 512; i += stride) {
        int n = i >> 9, k = i & 511;
        W3sum[i] = W3[n * 1024 + k] + W3[n * 1024 + 512 + k];
    }
}

// ---------------------------------------------------------------------------
// proj0: pre0[(seq*2+dir)][t][o] = x[t] @ Wih0[dir].T + b0sum[dir]
// ---------------------------------------------------------------------------
__global__ __launch_bounds__(256) void proj0_kernel(
    const float* __restrict__ v_r, const float* __restrict__ v_l,
    const float* __restrict__ Wih0, const float* __restrict__ b0sum,
    float* __restrict__ pre0)
{
    int t = blockIdx.x;
    int sd = blockIdx.y;            // seq*2 + dir
    int seq = sd >> 1, dir = sd & 1;
    const float* x = (seq ? v_l : v_r) + t * 22;
    __shared__ float sx[22];
    if (threadIdx.x < 22) sx[threadIdx.x] = x[threadIdx.x];
    __syncthreads();
#pragma unroll
    for (int q = 0; q < 4; ++q) {
        int o = q * 256 + threadIdx.x;
        const float* wr = Wih0 + (size_t)(dir * 1024 + o) * 22;
        float acc = b0sum[dir * 1024 + o];
#pragma unroll
        for (int d = 0; d < 22; ++d) acc += sx[d] * wr[d];
        pre0[((size_t)sd * 384 + t) * 1024 + o] = acc;
    }
}

// ---------------------------------------------------------------------------
// LSTM recurrence, v9: RT-HIDING via own-half/remote-half matvec split.
// R8 post-mortem: 3 structural variants all ~3600-3700 cyc/step -> the
// publish->poll L2 round trip (~1500-2000 cyc) is serially exposed; barrier
// count is irrelevant. v9 overlaps it with compute:
//   per step s: [own-half fdot (k in own WG's 128, h produced locally)]
//               [isPoll lanes: poll peer h_{s-1} -> hh[par] remote region]
//               [barrier]  (RT hidden behind own-half fdot window)
//               [remote-half fdot] [butterfly + pre + gates -> h_s, all lanes]
//               [isPub: pair -> hh[pn] own region + tagged publish (tag s+1)]
//               [isOut: out store  (ack drains at end barrier)]
//               [barrier]
// Deadlock-free by induction: publish(s) needs only poll(s)=peer tag s from
// peer's iter s-1; iter-0 polls nothing (h_{-1}=0 prefilled). Slot reuse
// safe: observing peer tag s implies peer finished its tag s-1 poll (their
// mid-barrier orders poll before publish).
// Carried lessons: lane roles with publish-before-poll program order (R4),
// pinned f16 weights vs remat (R2), fdot2 fp32 accumulation (R7), all-lane
// redundant bit-identical cstate (R8), bounded s_sleep spin (R4).
// hh: [2 parity][128 pairs] flat; 16-pair blocks per (half,ks) -> 4 distinct
// b128 addrs/wave, 2-way bank aliasing = free.
// Grid 16: chain = b&7 (>=4 exits), w = b>>3 -> chain's 2 WGs on XCD chain.
// ---------------------------------------------------------------------------
__global__ __launch_bounds__(512, 2) void lstm_rec_kernel(
    const float* __restrict__ Whh,   // [2][1024][256] fp32
    const float* __restrict__ pre,   // layer0: [(seq*2+dir)][384][1024]; layer1: [(seq*384+t)][2][1024]
    float* __restrict__ out,         // [2][384][512]  (cols: dir*256 + j)
    unsigned long long* pub,         // [4 chains][2 parity][64]
    int layer)
{
    const int b = blockIdx.x;
    const int chain = b & 7;                 // = XCD id under %8 round-robin
    const int w = b >> 3;                    // 0 or 1
    if (chain >= 4) return;
    const int seq = chain >> 1, dir = chain & 1;
    const int tid = threadIdx.x;
    const int ks = tid & 3;                  // k-sub-slice within each half
    const int r = tid >> 2;                  // 0..127
    const int j = (w << 7) + r;              // own h index in [0,256)
    const int wp = 1 - w;

    __shared__ __align__(16) half2_t hh[2][128];   // [parity][pair]; pair P = h{2P,2P+1}

    // Weights f16: 4 gates x (16 own + 16 remote) half2 = 128 VGPRs, pinned.
    // own k: [w*128 + 32ks, +32); remote k: [wp*128 + 32ks, +32).
    float wto[4][16], wtr[4][16];
#pragma unroll
    for (int g = 0; g < 4; ++g) {
        const float* wrow = Whh + (((size_t)(dir * 1024 + g * 256 + j)) << 8);
        const float* po = wrow + (w << 7) + (ks << 5);
        const float* pr = wrow + (wp << 7) + (ks << 5);
#pragma unroll
        for (int q = 0; q < 16; ++q) {
            float2 vo = *(const float2*)(po + 2 * q);
            float2 vr = *(const float2*)(pr + 2 * q);
            half2_t ho2; ho2.x = (_Float16)vo.x; ho2.y = (_Float16)vo.y;
            half2_t hr2; hr2.x = (_Float16)vr.x; hr2.y = (_Float16)vr.y;
            wto[g][q] = __builtin_bit_cast(float, ho2);
            wtr[g][q] = __builtin_bit_cast(float, hr2);
        }
    }
#pragma unroll
    for (int g = 0; g < 4; ++g)
#pragma unroll
        for (int q = 0; q < 16; ++q)
            asm volatile("" : "+v"(wto[g][q]), "+v"(wtr[g][q]));

    if (tid < 128) {
        hh[0][tid] = half2_t{(_Float16)0.f, (_Float16)0.f};
        hh[1][tid] = half2_t{(_Float16)0.f, (_Float16)0.f};
    }
    float cstate = 0.f;                      // redundant, bit-identical in 4 k-lanes

    const bool isPub  = (ks == 0) && ((r & 1) == 0);   // tid%8==0
    const bool isOut  = (ks == 1);
    const bool isPoll = (ks == 3) && ((r & 1) == 1);   // tid%8==7
    const int  p  = r >> 1;                  // pair index 0..63
    __syncthreads();

    for (int s = 0; s < 384; ++s) {
        const int t = dir ? (383 - s) : s;
        const float* pre_t = (layer == 0)
            ? pre + ((size_t)(seq * 2 + dir) * 384 + t) * 1024
            : pre + (((size_t)(seq * 384 + t)) * 2 + dir) * 1024;
        float pv = pre_t[(ks << 8) + j];     // early issue, drains during fdot

        const int par = s & 1;
        // ---- Phase A: own-half fdot (h_{s-1} own region, locally written) ----
        float a0 = 0.f, a1 = 0.f, a2 = 0.f, a3 = 0.f;
        {
            const float4* ro = (const float4*)&hh[par][(w << 6) + (ks << 4)];
            float4 ho[4];
#pragma unroll
            for (int m = 0; m < 4; ++m) ho[m] = ro[m];
#pragma unroll
            for (int m = 0; m < 4; ++m) {
                const float he[4] = {ho[m].x, ho[m].y, ho[m].z, ho[m].w};
#pragma unroll
                for (int e = 0; e < 4; ++e) {
                    half2_t hv = __builtin_bit_cast(half2_t, he[e]);
                    int q = 4 * m + e;
                    a0 = __builtin_amdgcn_fdot2(__builtin_bit_cast(half2_t, wto[0][q]), hv, a0, false);
                    a1 = __builtin_amdgcn_fdot2(__builtin_bit_cast(half2_t, wto[1][q]), hv, a1, false);
                    a2 = __builtin_amdgcn_fdot2(__builtin_bit_cast(half2_t, wto[2][q]), hv, a2, false);
                    a3 = __builtin_amdgcn_fdot2(__builtin_bit_cast(half2_t, wto[3][q]), hv, a3, false);
                }
            }
        }
        // ---- Poll peer h_{s-1} (tag s) — overlapped with phase A above ----
        if (isPoll && s > 0) {
            unsigned long long* pb = pub + ((size_t)chain * 2 + par) * 64;
            const unsigned long long* src = &pb[(wp << 6) + p];
            const unsigned expect = (unsigned)s;
            unsigned long long v =
                __hip_atomic_load(src, __ATOMIC_RELAXED, __HIP_MEMORY_SCOPE_AGENT);
            if ((unsigned)(v >> 32) != expect) {
                for (int it = 0; it < 65536; ++it) {
                    __builtin_amdgcn_s_sleep(1);
                    v = __hip_atomic_load(src, __ATOMIC_RELAXED, __HIP_MEMORY_SCOPE_AGENT);
                    if ((unsigned)(v >> 32) == expect) break;
                }
            }
            hh[par][(wp << 6) + p] = __builtin_bit_cast(half2_t, (unsigned)v);
        }
        __syncthreads();                     // remote h_{s-1} visible

        // ---- Phase B: remote-half fdot ----
        {
            const float4* rr = (const float4*)&hh[par][(wp << 6) + (ks << 4)];
            float4 hr[4];
#pragma unroll
            for (int m = 0; m < 4; ++m) hr[m] = rr[m];
#pragma unroll
            for (int m = 0; m < 4; ++m) {
                const float he[4] = {hr[m].x, hr[m].y, hr[m].z, hr[m].w};
#pragma unroll
                for (int e = 0; e < 4; ++e) {
                    half2_t hv = __builtin_bit_cast(half2_t, he[e]);
                    int q = 4 * m + e;
                    a0 = __builtin_amdgcn_fdot2(__builtin_bit_cast(half2_t, wtr[0][q]), hv, a0, false);
                    a1 = __builtin_amdgcn_fdot2(__builtin_bit_cast(half2_t, wtr[1][q]), hv, a1, false);
                    a2 = __builtin_amdgcn_fdot2(__builtin_bit_cast(half2_t, wtr[2][q]), hv, a2, false);
                    a3 = __builtin_amdgcn_fdot2(__builtin_bit_cast(half2_t, wtr[3][q]), hv, a3, false);
                }
            }
        }
        // Fold pre exactly once (lane ks owns gate ks), butterfly over 4 lanes.
        a0 += (ks == 0) ? pv : 0.f;
        a1 += (ks == 1) ? pv : 0.f;
        a2 += (ks == 2) ? pv : 0.f;
        a3 += (ks == 3) ? pv : 0.f;
#pragma unroll
        for (int d = 1; d < 4; d <<= 1) {
            a0 += __shfl_xor(a0, d);
            a1 += __shfl_xor(a1, d);
            a2 += __shfl_xor(a2, d);
            a3 += __shfl_xor(a3, d);
        }

        // All lanes: redundant gate update (bit-identical across the 4 lanes).
        float iv = fast_sig(a0);
        float fv = fast_sig(a1);
        float gv = fast_tanh(a2);
        float ov = fast_sig(a3);
        cstate = fv * cstate + iv * gv;
        float h = ov * fast_tanh(cstate);

        unsigned hb = (unsigned)__builtin_bit_cast(unsigned short, (_Float16)h);
        unsigned nb = (unsigned)__shfl_xor((int)hb, 4);   // partner row r+1
        const int pn = par ^ 1;
        if (isPub) {
            unsigned payload = (hb & 0xffffu) | (nb << 16);
            int P = (w << 6) + p;
            hh[pn][P] = __builtin_bit_cast(half2_t, payload);
            unsigned long long pk =
                ((unsigned long long)(unsigned)(s + 1) << 32) | payload;
            __hip_atomic_store(&pub[((size_t)chain * 2 + pn) * 64 + P], pk,
                               __ATOMIC_RELAXED, __HIP_MEMORY_SCOPE_AGENT);
        }
        if (isOut) {
            out[((size_t)seq * 384 + t) * 512 + dir * 256 + j] = h;
        }
        __syncthreads();                     // own h_s pairs visible locally
    }
}

// ---------------------------------------------------------------------------
// Generic NT GEMM: C[M][N] = act(scale * A[M][K] @ W[N][K]^T + bias[N])
// ---------------------------------------------------------------------------
__global__ __launch_bounds__(256) void gemm_nt_kernel(
    const float* __restrict__ A, const float* __restrict__ W,
    const float* __restrict__ bias, float* __restrict__ C,
    int M, int N, int K, float scale, int do_relu)
{
    __shared__ float As[32][68];
    __shared__ float Ws[32][68];
    const int tid = threadIdx.x;
    const int n0 = blockIdx.x * 64, m0 = blockIdx.y * 64;
    const int lr = tid >> 2;
    const int lk = (tid & 3) * 8;
    const int tm = tid >> 4, tn = tid & 15;
    float acc[4][4];
#pragma unroll
    for (int i = 0; i < 4; ++i)
#pragma unroll
        for (int j = 0; j < 4; ++j) acc[i][j] = 0.f;

    for (int kc = 0; kc < K; kc += 32) {
        float4 a0 = *(const float4*)(A + (size_t)(m0 + lr) * K + kc + lk);
        float4 a1 = *(const float4*)(A + (size_t)(m0 + lr) * K + kc + lk + 4);
        float4 w0 = *(const float4*)(W + (size_t)(n0 + lr) * K + kc + lk);
        float4 w1 = *(const float4*)(W + (size_t)(n0 + lr) * K + kc + lk + 4);
        __syncthreads();
        As[lk + 0][lr] = a0.x; As[lk + 1][lr] = a0.y; As[lk + 2][lr] = a0.z; As[lk + 3][lr] = a0.w;
        As[lk + 4][lr] = a1.x; As[lk + 5][lr] = a1.y; As[lk + 6][lr] = a1.z; As[lk + 7][lr] = a1.w;
        Ws[lk + 0][lr] = w0.x; Ws[lk + 1][lr] = w0.y; Ws[lk + 2][lr] = w0.z; Ws[lk + 3][lr] = w0.w;
        Ws[lk + 4][lr] = w1.x; Ws[lk + 5][lr] = w1.y; Ws[lk + 6][lr] = w1.z; Ws[lk + 7][lr] = w1.w;
        __syncthreads();
#pragma unroll
        for (int kk = 0; kk < 32; ++kk) {
            float4 av = *(const float4*)&As[kk][tm * 4];
            float4 wv = *(const float4*)&Ws[kk][tn * 4];
            acc[0][0] += av.x * wv.x; acc[0][1] += av.x * wv.y; acc[0][2] += av.x * wv.z; acc[0][3] += av.x * wv.w;
            acc[1][0] += av.y * wv.x; acc[1][1] += av.y * wv.y; acc[1][2] += av.y * wv.z; acc[1][3] += av.y * wv.w;
            acc[2][0] += av.z * wv.x; acc[2][1] += av.z * wv.y; acc[2][2] += av.z * wv.z; acc[2][3] += av.z * wv.w;
            acc[3][0] += av.w * wv.x; acc[3][1] += av.w * wv.y; acc[3][2] += av.w * wv.z; acc[3][3] += av.w * wv.w;
        }
    }
    float4 bv = make_float4(0.f, 0.f, 0.f, 0.f);
    if (bias) bv = *(const float4*)(bias + n0 + tn * 4);
#pragma unroll
    for (int i = 0; i < 4; ++i) {
        int m = m0 + tm * 4 + i;
        float4 v;
        v.x = scale * acc[i][0] + bv.x;
        v.y = scale * acc[i][1] + bv.y;
        v.z = scale * acc[i][2] + bv.z;
        v.w = scale * acc[i][3] + bv.w;
        if (do_relu) {
            v.x = fmaxf(v.x, 0.f); v.y = fmaxf(v.y, 0.f);
            v.z = fmaxf(v.z, 0.f); v.w = fmaxf(v.w, 0.f);
        }
        *(float4*)(C + (size_t)m * N + n0 + tn * 4) = v;
    }
}

// ---------------------------------------------------------------------------
// pairwise: out[i][j][:] = log_softmax( sum_c relu(ur'[i][c]+ul[j][c]) * woutT[c][:] + bout )
// Stride 132 + row remap (il=ii/ii+16, jl=jj/jj+16) -> <=2-way conflicts (R7 fix).
// ---------------------------------------------------------------------------
__global__ __launch_bounds__(256) void pairwise_kernel(
    const float* __restrict__ u,      // [768][1024]
    const float* __restrict__ woutT,  // [1024][2]
    const float* __restrict__ bout,   // [2]
    float* __restrict__ out)          // [384][384][2]
{
    __shared__ float Ur[32][132];
    __shared__ float Ul[32][132];
    __shared__ float Wo[256];
    const int tid = threadIdx.x;
    const int j0 = blockIdx.x * 32, i0 = blockIdx.y * 32;
    const int ii = tid >> 4, jj = tid & 15;
    const int il0 = ii, il1 = ii + 16;
    const int jl0 = jj, jl1 = jj + 16;
    float acc000 = 0.f, acc001 = 0.f, acc010 = 0.f, acc011 = 0.f;
    float acc100 = 0.f, acc101 = 0.f, acc110 = 0.f, acc111 = 0.f;
    const int lrw = tid >> 3;
    const int lcb = (tid & 7) * 16;

    for (int cc = 0; cc < 1024; cc += 128) {
        __syncthreads();
#pragma unroll
        for (int q = 0; q < 4; ++q) {
            *(float4*)&Ur[lrw][lcb + 4 * q] =
                *(const float4*)(u + (size_t)(i0 + lrw) * 1024 + cc + lcb + 4 * q);
            *(float4*)&Ul[lrw][lcb + 4 * q] =
                *(const float4*)(u + (size_t)(384 + j0 + lrw) * 1024 + cc + lcb + 4 * q);
        }
        if (tid < 128)
            *(float2*)&Wo[tid * 2] = *(const float2*)(woutT + (size_t)(cc + tid) * 2);
        __syncthreads();

        for (int c = 0; c < 128; c += 4) {
            float4 a0  = *(const float4*)&Ur[il0][c];
            float4 a1  = *(const float4*)&Ur[il1][c];
            float4 b0v = *(const float4*)&Ul[jl0][c];
            float4 b1v = *(const float4*)&Ul[jl1][c];
            float4 wA4 = *(const float4*)&Wo[c * 2];
            float4 wB4 = *(const float4*)&Wo[c * 2 + 4];
#define PW_STEP(AX, W0, W1)                                   \
            { float rr;                                       \
              rr = fmaxf(a0.AX + b0v.AX, 0.f); acc000 += rr*(W0); acc001 += rr*(W1); \
              rr = fmaxf(a0.AX + b1v.AX, 0.f); acc010 += rr*(W0); acc011 += rr*(W1); \
              rr = fmaxf(a1.AX + b0v.AX, 0.f); acc100 += rr*(W0); acc101 += rr*(W1); \
              rr = fmaxf(a1.AX + b1v.AX, 0.f); acc110 += rr*(W0); acc111 += rr*(W1); }
            PW_STEP(x, wA4.x, wA4.y)
            PW_STEP(y, wA4.z, wA4.w)
            PW_STEP(z, wB4.x, wB4.y)
            PW_STEP(w, wB4.z, wB4.w)
#undef PW_STEP
        }
    }
    float2 bo = *(const float2*)bout;
    float pa[2][2][2] = {{{acc000, acc001}, {acc010, acc011}},
                         {{acc100, acc101}, {acc110, acc111}}};
#pragma unroll
    for (int pi = 0; pi < 2; ++pi)
#pragma unroll
        for (int pj = 0; pj < 2; ++pj) {
            float l0 = pa[pi][pj][0] + bo.x;
            float l1 = pa[pi][pj][1] + bo.y;
            float m = fmaxf(l0, l1);
            float lse = m + logf(expf(l0 - m) + expf(l1 - m));
            int ig = i0 + ii + 16 * pi;
            int jg = j0 + jj + 16 * pj;
            float2 o2; o2.x = l0 - lse; o2.y = l1 - lse;
            *(float2*)(out + ((size_t)ig * 384 + jg) * 2) = o2;
        }
}

// ---------------------------------------------------------------------------
extern "C" void kernel_launch(void* const* d_in, const int* in_sizes, int n_in,
                              void* d_out, int out_size, void* d_ws, size_t ws_size,
                              hipStream_t stream)
{
    const float* v_r  = (const float*)d_in[0];
    const float* v_l  = (const float*)d_in[1];
    const float* Wih0 = (const float*)d_in[2];
    const float* Whh0 = (const float*)d_in[3];
    const float* bih0 = (const float*)d_in[4];
    const float* bhh0 = (const float*)d_in[5];
    const float* Wih1 = (const float*)d_in[6];
    const float* Whh1 = (const float*)d_in[7];
    const float* bih1 = (const float*)d_in[8];
    const float* bhh1 = (const float*)d_in[9];
    const float* W1   = (const float*)d_in[10];
    const float* b1   = (const float*)d_in[11];
    const float* W2   = (const float*)d_in[12];
    const float* b2   = (const float*)d_in[13];
    const float* W3   = (const float*)d_in[14];
    const float* b3   = (const float*)d_in[15];
    const float* Wout = (const float*)d_in[16];
    const float* bout = (const float*)d_in[17];
    float* out = (float*)d_out;

    float* ws = (float*)d_ws;
    size_t off = 0;
    float* b0sum = ws + off; off += 2048;
    float* b1sum = ws + off; off += 2048;
    float* W3sum = ws + off; off += 1024 * 512;
    float* woutT = ws + off; off += 2048;
    float* pre0  = ws + off; off += (size_t)4 * 384 * 1024;
    float* out0  = ws + off; off += (size_t)2 * 384 * 512;
    float* pre1  = ws + off; off += (size_t)768 * 2048;
    float* out1  = ws + off; off += (size_t)2 * 384 * 512;
    float* h1    = ws + off; off += (size_t)768 * 1024;
    float* h2    = ws + off; off += (size_t)768 * 512;
    float* u     = ws + off; off += (size_t)768 * 1024;
    unsigned long long* pub0 = (unsigned long long*)(ws + off); off += 4 * 2 * 64 * 2;
    unsigned long long* pub1 = (unsigned long long*)(ws + off); off += 4 * 2 * 64 * 2;

    prep_kernel<<<512, 256, 0, stream>>>(bih0, bhh0, bih1, bhh1, W3, Wout,
                                         b0sum, b1sum, W3sum, woutT);
    proj0_kernel<<<dim3(384, 4), 256, 0, stream>>>(v_r, v_l, Wih0, b0sum, pre0);
    lstm_rec_kernel<<<16, 512, 0, stream>>>(Whh0, pre0, out0, pub0, 0);
    gemm_nt_kernel<<<dim3(2048 / 64, 768 / 64), 256, 0, stream>>>(
        out0, Wih1, b1sum, pre1, 768, 2048, 512, 1.f, 0);
    lstm_rec_kernel<<<16, 512, 0, stream>>>(Whh1, pre1, out1, pub1, 1);
    gemm_nt_kernel<<<dim3(1024 / 64, 768 / 64), 256, 0, stream>>>(
        out1, W1, b1, h1, 768, 1024, 512, 1.f, 1);
    gemm_nt_kernel<<<dim3(512 / 64, 768 / 64), 256, 0, stream>>>(
        h1, W2, b2, h2, 768, 512, 1024, 1.f, 1);
    gemm_nt_kernel<<<dim3(1024 / 64, 384 / 64), 256, 0, stream>>>(
        h2, W3sum, b3, u, 384, 1024, 512, 0.5f, 0);
    gemm_nt_kernel<<<dim3(1024 / 64, 384 / 64), 256, 0, stream>>>(
        h2 + (size_t)384 * 512, W3sum, nullptr, u + (size_t)384 * 1024, 384, 1024, 512, 0.5f, 0);
    pairwise_kernel<<<dim3(12, 12), 256, 0, stream>>>(u, woutT, bout, out);
}

// Round 10
// 1395.418 us; speedup vs baseline: 15.5122x; 15.5122x over previous
//
#include <hip/hip_runtime.h>
#include <math.h>

// Problem constants
// H=256, D_IN=22, T=384, 4H=1024, N_R=N_L=384, H1=1024, H2=512, H3=1024, RRI=2

typedef _Float16 half2_t __attribute__((ext_vector_type(2)));

__device__ __forceinline__ float fast_sig(float x) {
    float e = __expf(-x);
    return __builtin_amdgcn_rcpf(1.f + e);
}
__device__ __forceinline__ float fast_tanh(float x) {
    x = fminf(fmaxf(x, -30.f), 30.f);
    float e = __expf(2.f * x);
    return (e - 1.f) * __builtin_amdgcn_rcpf(e + 1.f);
}

// ---------------------------------------------------------------------------
// prep: b0sum = bih0+bhh0, b1sum = bih1+bhh1, W3sum[n][k] = W3[n][k]+W3[n][512+k],
//       woutT[2c+k] = Wout[k][c]
// ---------------------------------------------------------------------------
__global__ __launch_bounds__(256) void prep_kernel(
    const float* __restrict__ bih0, const float* __restrict__ bhh0,
    const float* __restrict__ bih1, const float* __restrict__ bhh1,
    const float* __restrict__ W3,   const float* __restrict__ Wout,
    float* __restrict__ b0sum, float* __restrict__ b1sum,
    float* __restrict__ W3sum, float* __restrict__ woutT)
{
    int idx = blockIdx.x * 256 + threadIdx.x;
    int stride = gridDim.x * 256;
    if (idx < 2048) {
        b0sum[idx] = bih0[idx] + bhh0[idx];
        b1sum[idx] = bih1[idx] + bhh1[idx];
        woutT[idx] = Wout[(idx & 1) * 1024 + (idx >> 1)];
    }
    for (int i = idx; i < 1024 * 512; i += stride) {
        int n = i >> 9, k = i & 511;
        W3sum[i] = W3[n * 1024 + k] + W3[n * 1024 + 512 + k];
    }
}

// ---------------------------------------------------------------------------
// proj0: pre0[(seq*2+dir)][t][o] = x[t] @ Wih0[dir].T + b0sum[dir]
// ---------------------------------------------------------------------------
__global__ __launch_bounds__(256) void proj0_kernel(
    const float* __restrict__ v_r, const float* __restrict__ v_l,
    const float* __restrict__ Wih0, const float* __restrict__ b0sum,
    float* __restrict__ pre0)
{
    int t = blockIdx.x;
    int sd = blockIdx.y;            // seq*2 + dir
    int seq = sd >> 1, dir = sd & 1;
    const float* x = (seq ? v_l : v_r) + t * 22;
    __shared__ float sx[22];
    if (threadIdx.x < 22) sx[threadIdx.x] = x[threadIdx.x];
    __syncthreads();
#pragma unroll
    for (int q = 0; q < 4; ++q) {
        int o = q * 256 + threadIdx.x;
        const float* wr = Wih0 + (size_t)(dir * 1024 + o) * 22;
        float acc = b0sum[dir * 1024 + o];
#pragma unroll
        for (int d = 0; d < 22; ++d) acc += sx[d] * wr[d];
        pre0[((size_t)sd * 384 + t) * 1024 + o] = acc;
    }
}

// ---------------------------------------------------------------------------
// LSTM recurrence, v10 = v9 with the pub BOUNDS BUG fixed.
// R9 root cause: pub was sized [2 parity][64]/chain but indexed with the v8
// global pair index P=(w<<6)+p in [0,128) -> WG w=1 published into the next
// parity/chain block (and past the allocation) -> cross-chain tag corruption
// -> spin-cap timeouts (~1.75 ms each), 18 ms dispatches, stale h.
// Fix: pub = [4 chains][2 parity][128 pairs]; publish & poll use stride 128.
//
// Structure (v9): RT-hiding via own-half/remote-half matvec split.
//   per step s: [own-half fdot (local h)] [isPoll: poll peer h_{s-1} tag s]
//               [barrier] [remote-half fdot] [butterfly+pre+gates -> h_s]
//               [isPub: hh[pn] + tagged publish tag s+1] [isOut: out store]
//               [barrier]
// The publish->poll L2 RT overlaps the own-half fdot window instead of being
// serially exposed (R8 lesson: barrier count doesn't matter, the RT does).
// Deadlock-free by induction; slot reuse safe (observing peer tag s+2
// implies peer consumed tag s+1). Carried: lane roles w/ publish-before-poll
// (R4), pinned f16 weights (R2), fdot2 fp32 accum (R7), all-lane redundant
// bit-identical cstate (R8), bounded s_sleep spin (R4).
// Grid 16: chain = b&7 (>=4 exits), w = b>>3 -> chain's 2 WGs on XCD chain.
// ---------------------------------------------------------------------------
__global__ __launch_bounds__(512, 2) void lstm_rec_kernel(
    const float* __restrict__ Whh,   // [2][1024][256] fp32
    const float* __restrict__ pre,   // layer0: [(seq*2+dir)][384][1024]; layer1: [(seq*384+t)][2][1024]
    float* __restrict__ out,         // [2][384][512]  (cols: dir*256 + j)
    unsigned long long* pub,         // [4 chains][2 parity][128]
    int layer)
{
    const int b = blockIdx.x;
    const int chain = b & 7;                 // = XCD id under %8 round-robin
    const int w = b >> 3;                    // 0 or 1
    if (chain >= 4) return;
    const int seq = chain >> 1, dir = chain & 1;
    const int tid = threadIdx.x;
    const int ks = tid & 3;                  // k-sub-slice within each half
    const int r = tid >> 2;                  // 0..127
    const int j = (w << 7) + r;              // own h index in [0,256)
    const int wp = 1 - w;

    __shared__ __align__(16) half2_t hh[2][128];   // [parity][pair]; pair P = h{2P,2P+1}

    // Weights f16: 4 gates x (16 own + 16 remote) half2 = 128 VGPRs, pinned.
    float wto[4][16], wtr[4][16];
#pragma unroll
    for (int g = 0; g < 4; ++g) {
        const float* wrow = Whh + (((size_t)(dir * 1024 + g * 256 + j)) << 8);
        const float* po = wrow + (w << 7) + (ks << 5);
        const float* pr = wrow + (wp << 7) + (ks << 5);
#pragma unroll
        for (int q = 0; q < 16; ++q) {
            float2 vo = *(const float2*)(po + 2 * q);
            float2 vr = *(const float2*)(pr + 2 * q);
            half2_t ho2; ho2.x = (_Float16)vo.x; ho2.y = (_Float16)vo.y;
            half2_t hr2; hr2.x = (_Float16)vr.x; hr2.y = (_Float16)vr.y;
            wto[g][q] = __builtin_bit_cast(float, ho2);
            wtr[g][q] = __builtin_bit_cast(float, hr2);
        }
    }
#pragma unroll
    for (int g = 0; g < 4; ++g)
#pragma unroll
        for (int q = 0; q < 16; ++q)
            asm volatile("" : "+v"(wto[g][q]), "+v"(wtr[g][q]));

    if (tid < 128) {
        hh[0][tid] = half2_t{(_Float16)0.f, (_Float16)0.f};
        hh[1][tid] = half2_t{(_Float16)0.f, (_Float16)0.f};
    }
    float cstate = 0.f;                      // redundant, bit-identical in 4 k-lanes

    const bool isPub  = (ks == 0) && ((r & 1) == 0);   // tid%8==0
    const bool isOut  = (ks == 1);
    const bool isPoll = (ks == 3) && ((r & 1) == 1);   // tid%8==7
    const int  p  = r >> 1;                  // pair index 0..63
    __syncthreads();

    for (int s = 0; s < 384; ++s) {
        const int t = dir ? (383 - s) : s;
        const float* pre_t = (layer == 0)
            ? pre + ((size_t)(seq * 2 + dir) * 384 + t) * 1024
            : pre + (((size_t)(seq * 384 + t)) * 2 + dir) * 1024;
        float pv = pre_t[(ks << 8) + j];     // early issue, drains during fdot

        const int par = s & 1;
        // ---- Phase A: own-half fdot (h_{s-1} own region, locally written) ----
        float a0 = 0.f, a1 = 0.f, a2 = 0.f, a3 = 0.f;
        {
            const float4* ro = (const float4*)&hh[par][(w << 6) + (ks << 4)];
            float4 ho[4];
#pragma unroll
            for (int m = 0; m < 4; ++m) ho[m] = ro[m];
#pragma unroll
            for (int m = 0; m < 4; ++m) {
                const float he[4] = {ho[m].x, ho[m].y, ho[m].z, ho[m].w};
#pragma unroll
                for (int e = 0; e < 4; ++e) {
                    half2_t hv = __builtin_bit_cast(half2_t, he[e]);
                    int q = 4 * m + e;
                    a0 = __builtin_amdgcn_fdot2(__builtin_bit_cast(half2_t, wto[0][q]), hv, a0, false);
                    a1 = __builtin_amdgcn_fdot2(__builtin_bit_cast(half2_t, wto[1][q]), hv, a1, false);
                    a2 = __builtin_amdgcn_fdot2(__builtin_bit_cast(half2_t, wto[2][q]), hv, a2, false);
                    a3 = __builtin_amdgcn_fdot2(__builtin_bit_cast(half2_t, wto[3][q]), hv, a3, false);
                }
            }
        }
        // ---- Poll peer h_{s-1} (tag s) — overlapped with phase A above ----
        if (isPoll && s > 0) {
            unsigned long long* pb = pub + ((size_t)chain * 2 + par) * 128;
            const unsigned long long* src = &pb[(wp << 6) + p];
            const unsigned expect = (unsigned)s;
            unsigned long long v =
                __hip_atomic_load(src, __ATOMIC_RELAXED, __HIP_MEMORY_SCOPE_AGENT);
            if ((unsigned)(v >> 32) != expect) {
                for (int it = 0; it < 65536; ++it) {
                    __builtin_amdgcn_s_sleep(1);
                    v = __hip_atomic_load(src, __ATOMIC_RELAXED, __HIP_MEMORY_SCOPE_AGENT);
                    if ((unsigned)(v >> 32) == expect) break;
                }
            }
            hh[par][(wp << 6) + p] = __builtin_bit_cast(half2_t, (unsigned)v);
        }
        __syncthreads();                     // remote h_{s-1} visible

        // ---- Phase B: remote-half fdot ----
        {
            const float4* rr = (const float4*)&hh[par][(wp << 6) + (ks << 4)];
            float4 hr[4];
#pragma unroll
            for (int m = 0; m < 4; ++m) hr[m] = rr[m];
#pragma unroll
            for (int m = 0; m < 4; ++m) {
                const float he[4] = {hr[m].x, hr[m].y, hr[m].z, hr[m].w};
#pragma unroll
                for (int e = 0; e < 4; ++e) {
                    half2_t hv = __builtin_bit_cast(half2_t, he[e]);
                    int q = 4 * m + e;
                    a0 = __builtin_amdgcn_fdot2(__builtin_bit_cast(half2_t, wtr[0][q]), hv, a0, false);
                    a1 = __builtin_amdgcn_fdot2(__builtin_bit_cast(half2_t, wtr[1][q]), hv, a1, false);
                    a2 = __builtin_amdgcn_fdot2(__builtin_bit_cast(half2_t, wtr[2][q]), hv, a2, false);
                    a3 = __builtin_amdgcn_fdot2(__builtin_bit_cast(half2_t, wtr[3][q]), hv, a3, false);
                }
            }
        }
        // Fold pre exactly once (lane ks owns gate ks), butterfly over 4 lanes.
        a0 += (ks == 0) ? pv : 0.f;
        a1 += (ks == 1) ? pv : 0.f;
        a2 += (ks == 2) ? pv : 0.f;
        a3 += (ks == 3) ? pv : 0.f;
#pragma unroll
        for (int d = 1; d < 4; d <<= 1) {
            a0 += __shfl_xor(a0, d);
            a1 += __shfl_xor(a1, d);
            a2 += __shfl_xor(a2, d);
            a3 += __shfl_xor(a3, d);
        }

        // All lanes: redundant gate update (bit-identical across the 4 lanes).
        float iv = fast_sig(a0);
        float fv = fast_sig(a1);
        float gv = fast_tanh(a2);
        float ov = fast_sig(a3);
        cstate = fv * cstate + iv * gv;
        float h = ov * fast_tanh(cstate);

        unsigned hb = (unsigned)__builtin_bit_cast(unsigned short, (_Float16)h);
        unsigned nb = (unsigned)__shfl_xor((int)hb, 4);   // partner row r+1
        const int pn = par ^ 1;
        if (isPub) {
            unsigned payload = (hb & 0xffffu) | (nb << 16);
            int P = (w << 6) + p;
            hh[pn][P] = __builtin_bit_cast(half2_t, payload);
            unsigned long long pk =
                ((unsigned long long)(unsigned)(s + 1) << 32) | payload;
            __hip_atomic_store(&pub[((size_t)chain * 2 + pn) * 128 + P], pk,
                               __ATOMIC_RELAXED, __HIP_MEMORY_SCOPE_AGENT);
        }
        if (isOut) {
            out[((size_t)seq * 384 + t) * 512 + dir * 256 + j] = h;
        }
        __syncthreads();                     // own h_s pairs visible locally
    }
}

// ---------------------------------------------------------------------------
// Generic NT GEMM: C[M][N] = act(scale * A[M][K] @ W[N][K]^T + bias[N])
// ---------------------------------------------------------------------------
__global__ __launch_bounds__(256) void gemm_nt_kernel(
    const float* __restrict__ A, const float* __restrict__ W,
    const float* __restrict__ bias, float* __restrict__ C,
    int M, int N, int K, float scale, int do_relu)
{
    __shared__ float As[32][68];
    __shared__ float Ws[32][68];
    const int tid = threadIdx.x;
    const int n0 = blockIdx.x * 64, m0 = blockIdx.y * 64;
    const int lr = tid >> 2;
    const int lk = (tid & 3) * 8;
    const int tm = tid >> 4, tn = tid & 15;
    float acc[4][4];
#pragma unroll
    for (int i = 0; i < 4; ++i)
#pragma unroll
        for (int j = 0; j < 4; ++j) acc[i][j] = 0.f;

    for (int kc = 0; kc < K; kc += 32) {
        float4 a0 = *(const float4*)(A + (size_t)(m0 + lr) * K + kc + lk);
        float4 a1 = *(const float4*)(A + (size_t)(m0 + lr) * K + kc + lk + 4);
        float4 w0 = *(const float4*)(W + (size_t)(n0 + lr) * K + kc + lk);
        float4 w1 = *(const float4*)(W + (size_t)(n0 + lr) * K + kc + lk + 4);
        __syncthreads();
        As[lk + 0][lr] = a0.x; As[lk + 1][lr] = a0.y; As[lk + 2][lr] = a0.z; As[lk + 3][lr] = a0.w;
        As[lk + 4][lr] = a1.x; As[lk + 5][lr] = a1.y; As[lk + 6][lr] = a1.z; As[lk + 7][lr] = a1.w;
        Ws[lk + 0][lr] = w0.x; Ws[lk + 1][lr] = w0.y; Ws[lk + 2][lr] = w0.z; Ws[lk + 3][lr] = w0.w;
        Ws[lk + 4][lr] = w1.x; Ws[lk + 5][lr] = w1.y; Ws[lk + 6][lr] = w1.z; Ws[lk + 7][lr] = w1.w;
        __syncthreads();
#pragma unroll
        for (int kk = 0; kk < 32; ++kk) {
            float4 av = *(const float4*)&As[kk][tm * 4];
            float4 wv = *(const float4*)&Ws[kk][tn * 4];
            acc[0][0] += av.x * wv.x; acc[0][1] += av.x * wv.y; acc[0][2] += av.x * wv.z; acc[0][3] += av.x * wv.w;
            acc[1][0] += av.y * wv.x; acc[1][1] += av.y * wv.y; acc[1][2] += av.y * wv.z; acc[1][3] += av.y * wv.w;
            acc[2][0] += av.z * wv.x; acc[2][1] += av.z * wv.y; acc[2][2] += av.z * wv.z; acc[2][3] += av.z * wv.w;
            acc[3][0] += av.w * wv.x; acc[3][1] += av.w * wv.y; acc[3][2] += av.w * wv.z; acc[3][3] += av.w * wv.w;
        }
    }
    float4 bv = make_float4(0.f, 0.f, 0.f, 0.f);
    if (bias) bv = *(const float4*)(bias + n0 + tn * 4);
#pragma unroll
    for (int i = 0; i < 4; ++i) {
        int m = m0 + tm * 4 + i;
        float4 v;
        v.x = scale * acc[i][0] + bv.x;
        v.y = scale * acc[i][1] + bv.y;
        v.z = scale * acc[i][2] + bv.z;
        v.w = scale * acc[i][3] + bv.w;
        if (do_relu) {
            v.x = fmaxf(v.x, 0.f); v.y = fmaxf(v.y, 0.f);
            v.z = fmaxf(v.z, 0.f); v.w = fmaxf(v.w, 0.f);
        }
        *(float4*)(C + (size_t)m * N + n0 + tn * 4) = v;
    }
}

// ---------------------------------------------------------------------------
// pairwise: out[i][j][:] = log_softmax( sum_c relu(ur'[i][c]+ul[j][c]) * woutT[c][:] + bout )
// Stride 132 + row remap (il=ii/ii+16, jl=jj/jj+16) -> <=2-way conflicts (R7 fix).
// ---------------------------------------------------------------------------
__global__ __launch_bounds__(256) void pairwise_kernel(
    const float* __restrict__ u,      // [768][1024]
    const float* __restrict__ woutT,  // [1024][2]
    const float* __restrict__ bout,   // [2]
    float* __restrict__ out)          // [384][384][2]
{
    __shared__ float Ur[32][132];
    __shared__ float Ul[32][132];
    __shared__ float Wo[256];
    const int tid = threadIdx.x;
    const int j0 = blockIdx.x * 32, i0 = blockIdx.y * 32;
    const int ii = tid >> 4, jj = tid & 15;
    const int il0 = ii, il1 = ii + 16;
    const int jl0 = jj, jl1 = jj + 16;
    float acc000 = 0.f, acc001 = 0.f, acc010 = 0.f, acc011 = 0.f;
    float acc100 = 0.f, acc101 = 0.f, acc110 = 0.f, acc111 = 0.f;
    const int lrw = tid >> 3;
    const int lcb = (tid & 7) * 16;

    for (int cc = 0; cc < 1024; cc += 128) {
        __syncthreads();
#pragma unroll
        for (int q = 0; q < 4; ++q) {
            *(float4*)&Ur[lrw][lcb + 4 * q] =
                *(const float4*)(u + (size_t)(i0 + lrw) * 1024 + cc + lcb + 4 * q);
            *(float4*)&Ul[lrw][lcb + 4 * q] =
                *(const float4*)(u + (size_t)(384 + j0 + lrw) * 1024 + cc + lcb + 4 * q);
        }
        if (tid < 128)
            *(float2*)&Wo[tid * 2] = *(const float2*)(woutT + (size_t)(cc + tid) * 2);
        __syncthreads();

        for (int c = 0; c < 128; c += 4) {
            float4 a0  = *(const float4*)&Ur[il0][c];
            float4 a1  = *(const float4*)&Ur[il1][c];
            float4 b0v = *(const float4*)&Ul[jl0][c];
            float4 b1v = *(const float4*)&Ul[jl1][c];
            float4 wA4 = *(const float4*)&Wo[c * 2];
            float4 wB4 = *(const float4*)&Wo[c * 2 + 4];
#define PW_STEP(AX, W0, W1)                                   \
            { float rr;                                       \
              rr = fmaxf(a0.AX + b0v.AX, 0.f); acc000 += rr*(W0); acc001 += rr*(W1); \
              rr = fmaxf(a0.AX + b1v.AX, 0.f); acc010 += rr*(W0); acc011 += rr*(W1); \
              rr = fmaxf(a1.AX + b0v.AX, 0.f); acc100 += rr*(W0); acc101 += rr*(W1); \
              rr = fmaxf(a1.AX + b1v.AX, 0.f); acc110 += rr*(W0); acc111 += rr*(W1); }
            PW_STEP(x, wA4.x, wA4.y)
            PW_STEP(y, wA4.z, wA4.w)
            PW_STEP(z, wB4.x, wB4.y)
            PW_STEP(w, wB4.z, wB4.w)
#undef PW_STEP
        }
    }
    float2 bo = *(const float2*)bout;
    float pa[2][2][2] = {{{acc000, acc001}, {acc010, acc011}},
                         {{acc100, acc101}, {acc110, acc111}}};
#pragma unroll
    for (int pi = 0; pi < 2; ++pi)
#pragma unroll
        for (int pj = 0; pj < 2; ++pj) {
            float l0 = pa[pi][pj][0] + bo.x;
            float l1 = pa[pi][pj][1] + bo.y;
            float m = fmaxf(l0, l1);
            float lse = m + logf(expf(l0 - m) + expf(l1 - m));
            int ig = i0 + ii + 16 * pi;
            int jg = j0 + jj + 16 * pj;
            float2 o2; o2.x = l0 - lse; o2.y = l1 - lse;
            *(float2*)(out + ((size_t)ig * 384 + jg) * 2) = o2;
        }
}

// ---------------------------------------------------------------------------
extern "C" void kernel_launch(void* const* d_in, const int* in_sizes, int n_in,
                              void* d_out, int out_size, void* d_ws, size_t ws_size,
                              hipStream_t stream)
{
    const float* v_r  = (const float*)d_in[0];
    const float* v_l  = (const float*)d_in[1];
    const float* Wih0 = (const float*)d_in[2];
    const float* Whh0 = (const float*)d_in[3];
    const float* bih0 = (const float*)d_in[4];
    const float* bhh0 = (const float*)d_in[5];
    const float* Wih1 = (const float*)d_in[6];
    const float* Whh1 = (const float*)d_in[7];
    const float* bih1 = (const float*)d_in[8];
    const float* bhh1 = (const float*)d_in[9];
    const float* W1   = (const float*)d_in[10];
    const float* b1   = (const float*)d_in[11];
    const float* W2   = (const float*)d_in[12];
    const float* b2   = (const float*)d_in[13];
    const float* W3   = (const float*)d_in[14];
    const float* b3   = (const float*)d_in[15];
    const float* Wout = (const float*)d_in[16];
    const float* bout = (const float*)d_in[17];
    float* out = (float*)d_out;

    float* ws = (float*)d_ws;
    size_t off = 0;
    float* b0sum = ws + off; off += 2048;
    float* b1sum = ws + off; off += 2048;
    float* W3sum = ws + off; off += 1024 * 512;
    float* woutT = ws + off; off += 2048;
    float* pre0  = ws + off; off += (size_t)4 * 384 * 1024;
    float* out0  = ws + off; off += (size_t)2 * 384 * 512;
    float* pre1  = ws + off; off += (size_t)768 * 2048;
    float* out1  = ws + off; off += (size_t)2 * 384 * 512;
    float* h1    = ws + off; off += (size_t)768 * 1024;
    float* h2    = ws + off; off += (size_t)768 * 512;
    float* u     = ws + off; off += (size_t)768 * 1024;
    unsigned long long* pub0 = (unsigned long long*)(ws + off); off += 4 * 2 * 128 * 2;
    unsigned long long* pub1 = (unsigned long long*)(ws + off); off += 4 * 2 * 128 * 2;

    prep_kernel<<<512, 256, 0, stream>>>(bih0, bhh0, bih1, bhh1, W3, Wout,
                                         b0sum, b1sum, W3sum, woutT);
    proj0_kernel<<<dim3(384, 4), 256, 0, stream>>>(v_r, v_l, Wih0, b0sum, pre0);
    lstm_rec_kernel<<<16, 512, 0, stream>>>(Whh0, pre0, out0, pub0, 0);
    gemm_nt_kernel<<<dim3(2048 / 64, 768 / 64), 256, 0, stream>>>(
        out0, Wih1, b1sum, pre1, 768, 2048, 512, 1.f, 0);
    lstm_rec_kernel<<<16, 512, 0, stream>>>(Whh1, pre1, out1, pub1, 1);
    gemm_nt_kernel<<<dim3(1024 / 64, 768 / 64), 256, 0, stream>>>(
        out1, W1, b1, h1, 768, 1024, 512, 1.f, 1);
    gemm_nt_kernel<<<dim3(512 / 64, 768 / 64), 256, 0, stream>>>(
        h1, W2, b2, h2, 768, 512, 1024, 1.f, 1);
    gemm_nt_kernel<<<dim3(1024 / 64, 384 / 64), 256, 0, stream>>>(
        h2, W3sum, b3, u, 384, 1024, 512, 0.5f, 0);
    gemm_nt_kernel<<<dim3(1024 / 64, 384 / 64), 256, 0, stream>>>(
        h2 + (size_t)384 * 512, W3sum, nullptr, u + (size_t)384 * 1024, 384, 1024, 512, 0.5f, 0);
    pairwise_kernel<<<dim3(12, 12), 256, 0, stream>>>(u, woutT, bout, out);
}